// Round 2
// baseline (605.397 us; speedup 1.0000x reference)
//
#include <hip/hip_runtime.h>
#include <math.h>

constexpr int F_IN  = 128;
constexpr int F_H   = 16;
constexpr int F_OUT = 2;
constexpr int SCAN_CHUNK = 2048;   // 256 threads x 8 elems

// ================= shared kernels =================

__global__ void deg_kernel(const int* __restrict__ dst, int E, int* __restrict__ deg) {
    int e = blockIdx.x * blockDim.x + threadIdx.x;
    if (e < E) atomicAdd(&deg[dst[e]], 1);
}

__global__ void dinv_kernel(const int* __restrict__ deg, float* __restrict__ dinv, int N) {
    int i = blockIdx.x * blockDim.x + threadIdx.x;
    if (i < N) dinv[i] = 1.0f / sqrtf((float)(deg[i] + 1));   // +1 = self-loop
}

// ---- h1 = x @ W1   (one thread per node row, W1 staged in LDS) ----
__global__ void gemm1_kernel(const float* __restrict__ x, const float* __restrict__ W1,
                             float* __restrict__ h1, int N) {
    __shared__ float w[F_IN * F_H];   // 8 KB
    for (int t = threadIdx.x; t < F_IN * F_H; t += blockDim.x) w[t] = W1[t];
    __syncthreads();
    int row = blockIdx.x * blockDim.x + threadIdx.x;
    if (row >= N) return;
    float acc[F_H];
#pragma unroll
    for (int j = 0; j < F_H; ++j) acc[j] = 0.0f;
    const float4* xr = (const float4*)(x + (size_t)row * F_IN);
#pragma unroll 4
    for (int k4 = 0; k4 < F_IN / 4; ++k4) {
        float4 v = xr[k4];
        const float* wr = &w[k4 * 4 * F_H];
#pragma unroll
        for (int j = 0; j < F_H; ++j)
            acc[j] += v.x * wr[j] + v.y * wr[F_H + j] + v.z * wr[2 * F_H + j] + v.w * wr[3 * F_H + j];
    }
    float4* hr = (float4*)(h1 + (size_t)row * F_H);
    hr[0] = make_float4(acc[0],  acc[1],  acc[2],  acc[3]);
    hr[1] = make_float4(acc[4],  acc[5],  acc[6],  acc[7]);
    hr[2] = make_float4(acc[8],  acc[9],  acc[10], acc[11]);
    hr[3] = make_float4(acc[12], acc[13], acc[14], acc[15]);
}

// ================= CSR build =================

// per-block exclusive scan of deg into cur; block totals to bsum
__global__ void scan_block_kernel(const int* __restrict__ deg, int* __restrict__ cur,
                                  int* __restrict__ bsum, int N) {
    __shared__ int sh[256];
    int tid = threadIdx.x;
    int base = blockIdx.x * SCAN_CHUNK + tid * 8;
    int v[8]; int sum = 0;
#pragma unroll
    for (int j = 0; j < 8; ++j) { int idx = base + j; v[j] = (idx < N) ? deg[idx] : 0; sum += v[j]; }
    sh[tid] = sum; __syncthreads();
    for (int off = 1; off < 256; off <<= 1) {
        int t = (tid >= off) ? sh[tid - off] : 0;
        __syncthreads();
        sh[tid] += t;
        __syncthreads();
    }
    if (tid == 255) bsum[blockIdx.x] = sh[255];
    int run = sh[tid] - sum;   // exclusive prefix for this thread
#pragma unroll
    for (int j = 0; j < 8; ++j) { int idx = base + j; if (idx < N) cur[idx] = run; run += v[j]; }
}

__global__ void scan_top_kernel(int* __restrict__ bsum, int nb) {
    if (threadIdx.x == 0 && blockIdx.x == 0) {
        int acc = 0;
        for (int i = 0; i < nb; ++i) { int t = bsum[i]; bsum[i] = acc; acc += t; }
    }
}

__global__ void scan_add_kernel(int* __restrict__ cur, const int* __restrict__ bsum, int N) {
    int i = blockIdx.x * blockDim.x + threadIdx.x;
    if (i < N) cur[i] += bsum[i >> 11];   // SCAN_CHUNK = 2048
}

// scatter edge srcs into dst-CSR slots; cur[d] ends at segment end
__global__ void scatter_kernel(const int* __restrict__ src, const int* __restrict__ dst,
                               int* __restrict__ cur, int* __restrict__ eidx, int E) {
    int e = blockIdx.x * blockDim.x + threadIdx.x;
    if (e >= E) return;
    int d = dst[e];
    int pos = atomicAdd(&cur[d], 1);
    eidx[pos] = src[e];
}

// ================= CSR aggregation =================

// layer-1 aggregation fused with bias+ReLU+W2 GEMM+out init. 16 lanes / node.
__global__ void agg1_fused_kernel(const int* __restrict__ eidx, const int* __restrict__ cur,
                                  const int* __restrict__ deg, const float* __restrict__ dinv,
                                  const float* __restrict__ h1, const float* __restrict__ b1,
                                  const float* __restrict__ W2, const float* __restrict__ b2,
                                  float* __restrict__ h2, float* __restrict__ out, int N) {
    int t = blockIdx.x * blockDim.x + threadIdx.x;
    int node = t >> 4;
    int lane = t & 15;
    if (node >= N) return;
    int cnt = deg[node];
    int start = cur[node] - cnt;   // cur ended at segment end after scatter
    float acc = 0.0f;
    for (int k0 = 0; k0 < cnt; k0 += 16) {
        int myk = k0 + lane;
        bool ok = myk < cnt;
        int sv = ok ? eidx[start + myk] : 0;     // 16 lanes: coalesced 64B
        float dv = ok ? dinv[sv] : 0.0f;         // lane-parallel gather
#pragma unroll
        for (int j = 0; j < 16; ++j) {           // broadcast + 16 independent line gathers
            int s   = __shfl(sv, j, 16);
            float w = __shfl(dv, j, 16);
            acc += h1[(size_t)s * F_H + lane] * w;
        }
    }
    float di = dinv[node];
    float y = acc * di + h1[(size_t)node * F_H + lane] * di * di + b1[lane];
    y = fmaxf(y, 0.0f);
    float p0 = y * W2[lane * F_OUT + 0];
    float p1 = y * W2[lane * F_OUT + 1];
#pragma unroll
    for (int m = 1; m < 16; m <<= 1) { p0 += __shfl_xor(p0, m); p1 += __shfl_xor(p1, m); }
    if (lane == 0) {
        ((float2*)h2)[node] = make_float2(p0, p1);
        ((float2*)out)[node] = make_float2(b2[0] + p0 * di * di, b2[1] + p1 * di * di);
    }
}

// layer-2 aggregation: 8 lanes / node, edge-strided, shuffle-reduced.
__global__ void agg2_fused_kernel(const int* __restrict__ eidx, const int* __restrict__ cur,
                                  const int* __restrict__ deg, const float* __restrict__ dinv,
                                  const float* __restrict__ h2, float* __restrict__ out, int N) {
    int t = blockIdx.x * blockDim.x + threadIdx.x;
    int node = t >> 3;
    int lane = t & 7;
    if (node >= N) return;
    int cnt = deg[node];
    int start = cur[node] - cnt;
    float a0 = 0.0f, a1 = 0.0f;
    for (int k = lane; k < cnt; k += 8) {
        int s = eidx[start + k];
        float2 v = ((const float2*)h2)[s];
        float w = dinv[s];
        a0 += v.x * w; a1 += v.y * w;
    }
#pragma unroll
    for (int m = 1; m < 8; m <<= 1) { a0 += __shfl_xor(a0, m); a1 += __shfl_xor(a1, m); }
    if (lane == 0) {
        float di = dinv[node];
        float2 o = ((float2*)out)[node];
        o.x += a0 * di; o.y += a1 * di;
        ((float2*)out)[node] = o;
    }
}

// ================= fallback (round-1 atomic path) =================

__global__ void agg1_atomic_kernel(const int* __restrict__ src, const int* __restrict__ dst,
                                   const float* __restrict__ dinv, const float* __restrict__ h1,
                                   float* __restrict__ agg1, int E) {
    int t = blockIdx.x * blockDim.x + threadIdx.x;
    int e = t >> 4; int lane = t & 15;
    if (e >= E) return;
    int s = src[e], d = dst[e];
    float nrm = dinv[s] * dinv[d];
    atomicAdd(&agg1[(size_t)d * F_H + lane], h1[(size_t)s * F_H + lane] * nrm);
}

__global__ void finalize_kernel(const float* __restrict__ agg1, const float* __restrict__ h1,
                                const float* __restrict__ dinv, const float* __restrict__ b1,
                                const float* __restrict__ W2, const float* __restrict__ b2,
                                float* __restrict__ h2, float* __restrict__ out, int N) {
    int i = blockIdx.x * blockDim.x + threadIdx.x;
    if (i >= N) return;
    float di2 = dinv[i] * dinv[i];
    float o0 = 0.0f, o1 = 0.0f;
#pragma unroll
    for (int j = 0; j < F_H; ++j) {
        float y = fmaxf(agg1[(size_t)i * F_H + j] + h1[(size_t)i * F_H + j] * di2 + b1[j], 0.0f);
        o0 += y * W2[j * F_OUT + 0];
        o1 += y * W2[j * F_OUT + 1];
    }
    ((float2*)h2)[i] = make_float2(o0, o1);
    ((float2*)out)[i] = make_float2(b2[0] + o0 * di2, b2[1] + o1 * di2);
}

__global__ void agg2_atomic_kernel(const int* __restrict__ src, const int* __restrict__ dst,
                                   const float* __restrict__ dinv, const float* __restrict__ h2,
                                   float* __restrict__ out, int E) {
    int t = blockIdx.x * blockDim.x + threadIdx.x;
    int e = t >> 1; int c = t & 1;
    if (e >= E) return;
    int s = src[e], d = dst[e];
    float nrm = dinv[s] * dinv[d];
    atomicAdd(&out[(size_t)d * F_OUT + c], h2[(size_t)s * F_OUT + c] * nrm);
}

// ================= launch =================

extern "C" void kernel_launch(void* const* d_in, const int* in_sizes, int n_in,
                              void* d_out, int out_size, void* d_ws, size_t ws_size,
                              hipStream_t stream) {
    const float* x  = (const float*)d_in[0];
    const int*   ei = (const int*)d_in[1];
    const float* W1 = (const float*)d_in[2];
    const float* b1 = (const float*)d_in[3];
    const float* W2 = (const float*)d_in[4];
    const float* b2 = (const float*)d_in[5];
    float* out = (float*)d_out;

    const int N = out_size / F_OUT;      // 100000
    const int E = in_sizes[1] / 2;       // 3200000
    const int* srcp = ei;
    const int* dstp = ei + E;

    const size_t szN4 = (size_t)N * 4;                 // 400 KB, 8B-aligned chunks
    const size_t need_csr = szN4 * 3 + 1024 + szN4 * F_H + szN4 * F_OUT + (size_t)E * 4;

    char* ws = (char*)d_ws;
    if (ws_size >= need_csr) {
        int*   deg  = (int*)ws;
        float* dinv = (float*)(ws + szN4);
        int*   cur  = (int*)(ws + szN4 * 2);
        int*   bsum = (int*)(ws + szN4 * 3);
        float* h1   = (float*)(ws + szN4 * 3 + 1024);
        float* h2   = (float*)(ws + szN4 * 3 + 1024 + szN4 * F_H);
        int*   eidx = (int*)(ws + szN4 * 3 + 1024 + szN4 * F_H + szN4 * F_OUT);

        const int nblk_scan = (N + SCAN_CHUNK - 1) / SCAN_CHUNK;   // 49

        hipMemsetAsync(deg, 0, szN4, stream);
        deg_kernel<<<(E + 255) / 256, 256, 0, stream>>>(dstp, E, deg);
        dinv_kernel<<<(N + 255) / 256, 256, 0, stream>>>(deg, dinv, N);
        scan_block_kernel<<<nblk_scan, 256, 0, stream>>>(deg, cur, bsum, N);
        scan_top_kernel<<<1, 64, 0, stream>>>(bsum, nblk_scan);
        scan_add_kernel<<<(N + 255) / 256, 256, 0, stream>>>(cur, bsum, N);
        scatter_kernel<<<(E + 255) / 256, 256, 0, stream>>>(srcp, dstp, cur, eidx, E);
        gemm1_kernel<<<(N + 255) / 256, 256, 0, stream>>>(x, W1, h1, N);
        agg1_fused_kernel<<<(N * 16 + 255) / 256, 256, 0, stream>>>(
            eidx, cur, deg, dinv, h1, b1, W2, b2, h2, out, N);
        agg2_fused_kernel<<<(N * 8 + 255) / 256, 256, 0, stream>>>(
            eidx, cur, deg, dinv, h2, out, N);
    } else {
        // fallback: round-1 atomic path (needs ~14.4 MB)
        int*   deg  = (int*)ws;
        float* dinv = (float*)(ws + szN4);
        float* h1   = (float*)(ws + szN4 * 2);
        float* agg1 = (float*)(ws + szN4 * (2 + F_H));
        float* h2   = (float*)(ws + szN4 * (2 + 2 * F_H));

        hipMemsetAsync(deg, 0, szN4, stream);
        hipMemsetAsync(agg1, 0, szN4 * F_H, stream);
        deg_kernel<<<(E + 255) / 256, 256, 0, stream>>>(dstp, E, deg);
        dinv_kernel<<<(N + 255) / 256, 256, 0, stream>>>(deg, dinv, N);
        gemm1_kernel<<<(N + 255) / 256, 256, 0, stream>>>(x, W1, h1, N);
        agg1_atomic_kernel<<<((size_t)E * 16 + 255) / 256, 256, 0, stream>>>(srcp, dstp, dinv, h1, agg1, E);
        finalize_kernel<<<(N + 255) / 256, 256, 0, stream>>>(agg1, h1, dinv, b1, W2, b2, h2, out, N);
        agg2_atomic_kernel<<<((size_t)E * 2 + 255) / 256, 256, 0, stream>>>(srcp, dstp, dinv, h2, out, E);
    }
}